// Round 1
// baseline (419.730 us; speedup 1.0000x reference)
//
#include <hip/hip_runtime.h>
#include <math.h>

#define HID 1024
#define VOCABN 50257

__device__ __forceinline__ float dot4(float4 a, float4 b) {
    return a.x * b.x + a.y * b.y + a.z * b.z + a.w * b.w;
}

__device__ __forceinline__ float sigmoidf(float x) {
    return 1.f / (1.f + expf(-x));
}

// One block (256 threads) per hidden unit u. Computes the 8 length-1024 dot
// products (rows u, H+u, 2H+u, 3H+u of W_ih and W_hh), then the LSTM cell
// update for unit u.
__global__ __launch_bounds__(256) void lstm_layer_kernel(
    const float* __restrict__ x_src, const int* __restrict__ idx, int use_idx,
    const float* __restrict__ h_in, const float* __restrict__ c_in,
    const float* __restrict__ W_ih, const float* __restrict__ W_hh,
    const float* __restrict__ b_ih, const float* __restrict__ b_hh,
    float* __restrict__ h_out, float* __restrict__ c_out)
{
    const int u = blockIdx.x;    // hidden unit 0..1023
    const int t = threadIdx.x;   // 0..255  (covers 1024 floats as float4)

    const float* x = x_src;
    if (use_idx) x += (size_t)(*idx) * HID;

    // x gets relu'd (reference applies relu before every lstm step)
    float4 xv = reinterpret_cast<const float4*>(x)[t];
    xv.x = fmaxf(xv.x, 0.f); xv.y = fmaxf(xv.y, 0.f);
    xv.z = fmaxf(xv.z, 0.f); xv.w = fmaxf(xv.w, 0.f);
    float4 hv = reinterpret_cast<const float4*>(h_in)[t];

    float acc[8];
#pragma unroll
    for (int g = 0; g < 4; ++g) {
        const float4* wi = reinterpret_cast<const float4*>(W_ih + (size_t)(g * HID + u) * HID);
        const float4* wh = reinterpret_cast<const float4*>(W_hh + (size_t)(g * HID + u) * HID);
        acc[g]     = dot4(wi[t], xv);
        acc[4 + g] = dot4(wh[t], hv);
    }

    // wave (64-lane) reduction of all 8 partials
#pragma unroll
    for (int off = 32; off > 0; off >>= 1) {
#pragma unroll
        for (int g = 0; g < 8; ++g) acc[g] += __shfl_down(acc[g], off);
    }

    __shared__ float red[4][8];
    const int wave = t >> 6, lane = t & 63;
    if (lane == 0) {
#pragma unroll
        for (int g = 0; g < 8; ++g) red[wave][g] = acc[g];
    }
    __syncthreads();

    if (t == 0) {
        float s[8];
#pragma unroll
        for (int g = 0; g < 8; ++g)
            s[g] = red[0][g] + red[1][g] + red[2][g] + red[3][g];
        float gi = s[0] + s[4] + b_ih[u]           + b_hh[u];
        float gf = s[1] + s[5] + b_ih[HID + u]     + b_hh[HID + u];
        float gg = s[2] + s[6] + b_ih[2 * HID + u] + b_hh[2 * HID + u];
        float go = s[3] + s[7] + b_ih[3 * HID + u] + b_hh[3 * HID + u];
        float i_ = sigmoidf(gi);
        float f_ = sigmoidf(gf);
        float g_ = tanhf(gg);
        float o_ = sigmoidf(go);
        float cn = f_ * c_in[u] + i_ * g_;
        float hn = o_ * tanhf(cn);
        h_out[u] = hn;
        c_out[u] = cn;
    }
}

// One wave per vocab row. 4 waves / block.
__global__ __launch_bounds__(256) void logits_kernel(
    const float* __restrict__ xh, const float* __restrict__ W_out,
    const float* __restrict__ b_out, float* __restrict__ logits)
{
    const int wave = threadIdx.x >> 6, lane = threadIdx.x & 63;
    const int v = blockIdx.x * 4 + wave;
    if (v >= VOCABN) return;

    const float4* w  = reinterpret_cast<const float4*>(W_out + (size_t)v * HID);
    const float4* x4 = reinterpret_cast<const float4*>(xh);
    float acc = 0.f;
#pragma unroll
    for (int j = 0; j < 4; ++j) {
        const int k = lane + j * 64;   // float4 index 0..255
        acc += dot4(w[k], x4[k]);
    }
#pragma unroll
    for (int off = 32; off > 0; off >>= 1) acc += __shfl_down(acc, off);
    if (lane == 0) logits[v] = acc + b_out[v];
}

// Single block, online logsumexp over VOCABN logits.
__global__ __launch_bounds__(1024) void lse_kernel(
    const float* __restrict__ logits, float* __restrict__ lse)
{
    const int t = threadIdx.x;
    float m = -1e30f, s = 0.f;
    for (int i = t; i < VOCABN; i += 1024) {
        float v = logits[i];
        if (v > m) { s = s * expf(m - v) + 1.f; m = v; }
        else       { s += expf(v - m); }
    }
#pragma unroll
    for (int off = 32; off > 0; off >>= 1) {
        float m2 = __shfl_down(m, off), s2 = __shfl_down(s, off);
        float mn = fmaxf(m, m2);
        s = s * expf(m - mn) + s2 * expf(m2 - mn);
        m = mn;
    }
    __shared__ float ms[16], ss[16];
    const int wave = t >> 6, lane = t & 63;
    if (lane == 0) { ms[wave] = m; ss[wave] = s; }
    __syncthreads();
    if (t == 0) {
        float M = ms[0], S = ss[0];
#pragma unroll
        for (int w = 1; w < 16; ++w) {
            float mn = fmaxf(M, ms[w]);
            S = S * expf(M - mn) + ss[w] * expf(ms[w] - mn);
            M = mn;
        }
        *lse = M + logf(S);
    }
}

__global__ __launch_bounds__(256) void finalize_kernel(
    const float* __restrict__ logits, const float* __restrict__ lse,
    float* __restrict__ out)
{
    const int i = blockIdx.x * 256 + threadIdx.x;
    if (i < VOCABN) out[i] = logits[i] - *lse;
}

extern "C" void kernel_launch(void* const* d_in, const int* in_sizes, int n_in,
                              void* d_out, int out_size, void* d_ws, size_t ws_size,
                              hipStream_t stream) {
    const int*   idx   = (const int*)d_in[0];
    const float* h0    = (const float*)d_in[1];
    const float* c0    = (const float*)d_in[2];
    const float* emb   = (const float*)d_in[3];
    const float* W_ih  = (const float*)d_in[4];
    const float* W_hh  = (const float*)d_in[5];
    const float* b_ih  = (const float*)d_in[6];
    const float* b_hh  = (const float*)d_in[7];
    const float* W_out = (const float*)d_in[8];
    const float* b_out = (const float*)d_in[9];

    float* out = (float*)d_out;              // [VOCAB] log-probs, then h [H], then c [H]
    float* h_final = out + VOCABN;
    float* c_final = out + VOCABN + HID;

    float* ws     = (float*)d_ws;
    float* h1     = ws;                      // [H]
    float* c1     = ws + HID;                // [H]
    float* logits = ws + 2 * HID;            // [VOCAB]
    float* lse    = ws + 2 * HID + VOCABN;   // [1]

    // Layer 1: x = relu(emb[idx]), h=h0, c=c0
    lstm_layer_kernel<<<HID, 256, 0, stream>>>(emb, idx, 1, h0, c0,
                                               W_ih, W_hh, b_ih, b_hh, h1, c1);
    // Layer 2: x = relu(h1), h=h1, c=c1 (same weights), write final h/c to d_out
    lstm_layer_kernel<<<HID, 256, 0, stream>>>(h1, nullptr, 0, h1, c1,
                                               W_ih, W_hh, b_ih, b_hh, h_final, c_final);
    // logits = h2 @ W_out^T + b_out
    logits_kernel<<<(VOCABN + 3) / 4, 256, 0, stream>>>(h_final, W_out, b_out, logits);
    // logsumexp
    lse_kernel<<<1, 1024, 0, stream>>>(logits, lse);
    // out = logits - lse
    finalize_kernel<<<(VOCABN + 255) / 256, 256, 0, stream>>>(logits, lse, out);
}

// Round 3
// 409.932 us; speedup vs baseline: 1.0239x; 1.0239x over previous
//
#include <hip/hip_runtime.h>
#include <math.h>

#define HID 1024
#define VOCABN 50257
#define ROWS_PER_BLOCK 16
#define NLOGB ((VOCABN + ROWS_PER_BLOCK - 1) / ROWS_PER_BLOCK)   // 3142

__device__ __forceinline__ float dot4(float4 a, float4 b) {
    return a.x * b.x + a.y * b.y + a.z * b.z + a.w * b.w;
}

__device__ __forceinline__ float sigmoidf_(float x) {
    return 1.f / (1.f + expf(-x));
}

// One block (256 threads) per hidden unit u. Computes the 8 length-1024 dot
// products (rows u, H+u, 2H+u, 3H+u of W_ih and W_hh), then the LSTM cell
// update for unit u.
__global__ __launch_bounds__(256) void lstm_layer_kernel(
    const float* __restrict__ x_src, const int* __restrict__ idx, int use_idx,
    const float* __restrict__ h_in, const float* __restrict__ c_in,
    const float* __restrict__ W_ih, const float* __restrict__ W_hh,
    const float* __restrict__ b_ih, const float* __restrict__ b_hh,
    float* __restrict__ h_out, float* __restrict__ c_out)
{
    const int u = blockIdx.x;    // hidden unit 0..1023
    const int t = threadIdx.x;   // 0..255  (covers 1024 floats as float4)

    const float* x = x_src;
    if (use_idx) x += (size_t)(*idx) * HID;

    // reference applies relu to x before every lstm step
    float4 xv = reinterpret_cast<const float4*>(x)[t];
    xv.x = fmaxf(xv.x, 0.f); xv.y = fmaxf(xv.y, 0.f);
    xv.z = fmaxf(xv.z, 0.f); xv.w = fmaxf(xv.w, 0.f);
    float4 hv = reinterpret_cast<const float4*>(h_in)[t];

    float acc[8];
#pragma unroll
    for (int g = 0; g < 4; ++g) {
        const float4* wi = reinterpret_cast<const float4*>(W_ih + (size_t)(g * HID + u) * HID);
        const float4* wh = reinterpret_cast<const float4*>(W_hh + (size_t)(g * HID + u) * HID);
        acc[g]     = dot4(wi[t], xv);
        acc[4 + g] = dot4(wh[t], hv);
    }

#pragma unroll
    for (int off = 32; off > 0; off >>= 1) {
#pragma unroll
        for (int g = 0; g < 8; ++g) acc[g] += __shfl_down(acc[g], off);
    }

    __shared__ float red[4][8];
    const int wave = t >> 6, lane = t & 63;
    if (lane == 0) {
#pragma unroll
        for (int g = 0; g < 8; ++g) red[wave][g] = acc[g];
    }
    __syncthreads();

    if (t == 0) {
        float s[8];
#pragma unroll
        for (int g = 0; g < 8; ++g)
            s[g] = red[0][g] + red[1][g] + red[2][g] + red[3][g];
        float gi = s[0] + s[4] + b_ih[u]           + b_hh[u];
        float gf = s[1] + s[5] + b_ih[HID + u]     + b_hh[HID + u];
        float gg = s[2] + s[6] + b_ih[2 * HID + u] + b_hh[2 * HID + u];
        float go = s[3] + s[7] + b_ih[3 * HID + u] + b_hh[3 * HID + u];
        float i_ = sigmoidf_(gi);
        float f_ = sigmoidf_(gf);
        float g_ = tanhf(gg);
        float o_ = sigmoidf_(go);
        float cn = f_ * c_in[u] + i_ * g_;
        float hn = o_ * tanhf(cn);
        h_out[u] = hn;
        c_out[u] = cn;
    }
}

// 4 waves/block, 4 vocab rows per wave (x held in registers, reused across
// rows). Also emits a per-block online-logsumexp partial (m, s).
__global__ __launch_bounds__(256) void logits_kernel(
    const float* __restrict__ xh, const float* __restrict__ W_out,
    const float* __restrict__ b_out, float* __restrict__ logits,
    float2* __restrict__ partials)
{
    const int wave = threadIdx.x >> 6, lane = threadIdx.x & 63;
    const int vbase = blockIdx.x * ROWS_PER_BLOCK + wave * 4;

    // x: 16 floats/lane in registers, reused for all 4 rows
    const float4* x4 = reinterpret_cast<const float4*>(xh);
    float4 xr[4];
#pragma unroll
    for (int j = 0; j < 4; ++j) xr[j] = x4[lane + j * 64];

    float acc[4];
#pragma unroll
    for (int r = 0; r < 4; ++r) {
        const int v = vbase + r;
        float a = 0.f;
        if (v < VOCABN) {
            const float4* w = reinterpret_cast<const float4*>(W_out + (size_t)v * HID);
#pragma unroll
            for (int j = 0; j < 4; ++j) a += dot4(w[lane + j * 64], xr[j]);
        }
        acc[r] = a;
    }
#pragma unroll
    for (int off = 32; off > 0; off >>= 1) {
#pragma unroll
        for (int r = 0; r < 4; ++r) acc[r] += __shfl_down(acc[r], off);
    }

    __shared__ float2 wred[4];
    if (lane == 0) {
        float m = -1e30f, s = 0.f;
#pragma unroll
        for (int r = 0; r < 4; ++r) {
            const int v = vbase + r;
            if (v < VOCABN) {
                float L = acc[r] + b_out[v];
                logits[v] = L;
                if (L > m) { s = s * expf(m - L) + 1.f; m = L; }
                else       { s += expf(L - m); }
            }
        }
        wred[wave] = make_float2(m, s);
    }
    __syncthreads();
    if (threadIdx.x == 0) {
        float M = wred[0].x, S = wred[0].y;
#pragma unroll
        for (int w = 1; w < 4; ++w) {
            float m2 = wred[w].x, s2 = wred[w].y;
            float mn = fmaxf(M, m2);
            S = S * expf(M - mn) + s2 * expf(m2 - mn);
            M = mn;
        }
        partials[blockIdx.x] = make_float2(M, S);
    }
}

// Each block redundantly merges the NLOGB (m,s) partials (25 KB, L2-hot),
// then writes its 256-element slice of out = logits - lse.
__global__ __launch_bounds__(256) void finalize_kernel(
    const float* __restrict__ logits, const float2* __restrict__ partials,
    float* __restrict__ out)
{
    const int t = threadIdx.x;
    float m = -1e30f, s = 0.f;
    for (int i = t; i < NLOGB; i += 256) {
        float2 p = partials[i];
        float mn = fmaxf(m, p.x);
        s = s * expf(m - mn) + p.y * expf(p.x - mn);
        m = mn;
    }
#pragma unroll
    for (int off = 32; off > 0; off >>= 1) {
        float m2 = __shfl_down(m, off), s2 = __shfl_down(s, off);
        float mn = fmaxf(m, m2);
        s = s * expf(m - mn) + s2 * expf(m2 - mn);
        m = mn;
    }
    __shared__ float ms[4], ss[4];
    __shared__ float lse_sh;
    const int wave = t >> 6, lane = t & 63;
    if (lane == 0) { ms[wave] = m; ss[wave] = s; }
    __syncthreads();
    if (t == 0) {
        float M = ms[0], S = ss[0];
#pragma unroll
        for (int w = 1; w < 4; ++w) {
            float mn = fmaxf(M, ms[w]);
            S = S * expf(M - mn) + ss[w] * expf(ms[w] - mn);
            M = mn;
        }
        lse_sh = M + logf(S);
    }
    __syncthreads();
    const float lse = lse_sh;
    const int i = blockIdx.x * 256 + t;
    if (i < VOCABN) out[i] = logits[i] - lse;
}

extern "C" void kernel_launch(void* const* d_in, const int* in_sizes, int n_in,
                              void* d_out, int out_size, void* d_ws, size_t ws_size,
                              hipStream_t stream) {
    const int*   idx   = (const int*)d_in[0];
    const float* h0    = (const float*)d_in[1];
    const float* c0    = (const float*)d_in[2];
    const float* emb   = (const float*)d_in[3];
    const float* W_ih  = (const float*)d_in[4];
    const float* W_hh  = (const float*)d_in[5];
    const float* b_ih  = (const float*)d_in[6];
    const float* b_hh  = (const float*)d_in[7];
    const float* W_out = (const float*)d_in[8];
    const float* b_out = (const float*)d_in[9];

    float* out = (float*)d_out;              // [VOCAB] log-probs, then h [H], then c [H]
    float* h_final = out + VOCABN;
    float* c_final = out + VOCABN + HID;

    float*  ws       = (float*)d_ws;
    float*  h1       = ws;                   // [H]
    float*  c1       = ws + HID;             // [H]
    float*  logits   = ws + 2 * HID;         // [VOCAB]
    float2* partials = (float2*)(ws + 2 * HID + VOCABN + 1);  // [NLOGB], 8B aligned

    // Layer 1: x = relu(emb[idx]), h=h0, c=c0
    lstm_layer_kernel<<<HID, 256, 0, stream>>>(emb, idx, 1, h0, c0,
                                               W_ih, W_hh, b_ih, b_hh, h1, c1);
    // Layer 2: x = relu(h1), h=h1, c=c1 (same weights), final h/c into d_out
    lstm_layer_kernel<<<HID, 256, 0, stream>>>(h1, nullptr, 0, h1, c1,
                                               W_ih, W_hh, b_ih, b_hh, h_final, c_final);
    // logits = h2 @ W_out^T + b_out, plus per-block lse partials
    logits_kernel<<<NLOGB, 256, 0, stream>>>(h_final, W_out, b_out, logits, partials);
    // out = logits - logsumexp(logits)
    finalize_kernel<<<(VOCABN + 255) / 256, 256, 0, stream>>>(logits, partials, out);
}